// Round 2
// baseline (2565.322 us; speedup 1.0000x reference)
//
#include <hip/hip_runtime.h>

#define TOK   16384   // B*T
#define DIM_  1024
#define QKV_N 3072
#define NH    16
#define HD    64
#define NF    256
#define TSEQ  4096
#define NCHUNK 8
#define CH_T  512     // TSEQ/NCHUNK
#define KVS   68      // kv row stride (64 d + 1 ksum + pad)

// bf16 <-> f32 bit helpers (deterministic, RNE)
__device__ __forceinline__ float bf2f(unsigned short u) {
  union { unsigned int i; float f; } c; c.i = ((unsigned int)u) << 16; return c.f;
}
__device__ __forceinline__ unsigned short f2bf(float f) {
  union { float f; unsigned int i; } c; c.f = f;
  unsigned int r = c.i + 0x7FFFu + ((c.i >> 16) & 1u);
  return (unsigned short)(r >> 16);
}

// ---------------- classic fp32 SGEMM: 128x128 tile, 8x8 microtile ----------------
// OutT = float (direct store) or unsigned short (bf16 store)
template<bool BIAS, typename OutT>
__global__ __launch_bounds__(256, 2)
void sgemm128(const float* __restrict__ A, const float* __restrict__ Bm,
              const float* __restrict__ bias, OutT* __restrict__ C,
              int M, int N, int K) {
  __shared__ float As[8][132];
  __shared__ float Bs[8][132];
  const int tid = threadIdx.x;
  const int tx = tid & 15;    // col group: cols {tx*4..+3} and {64+tx*4..+3}
  const int ty = tid >> 4;    // row group: rows ty*8..+7
  const int m0 = blockIdx.y * 128;
  const int n0 = blockIdx.x * 128;
  const int arow = tid >> 1;
  const int acol = (tid & 1) * 4;
  const int brow = tid >> 5;
  const int bcol = (tid & 31) * 4;
  const float* Aptr = A + (size_t)(m0 + arow) * K + acol;
  const float* Bptr = Bm + (size_t)brow * N + n0 + bcol;
  float c[8][8];
  #pragma unroll
  for (int i = 0; i < 8; i++)
    #pragma unroll
    for (int j = 0; j < 8; j++) c[i][j] = 0.f;

  for (int k0 = 0; k0 < K; k0 += 8) {
    const float4 av = *(const float4*)(Aptr + k0);
    const float4 bv = *(const float4*)(Bptr + (size_t)k0 * N);
    As[acol+0][arow] = av.x;
    As[acol+1][arow] = av.y;
    As[acol+2][arow] = av.z;
    As[acol+3][arow] = av.w;
    *(float4*)&Bs[brow][bcol] = bv;
    __syncthreads();
    #pragma unroll
    for (int kk = 0; kk < 8; kk++) {
      const float4 a0 = *(const float4*)&As[kk][ty*8];
      const float4 a1 = *(const float4*)&As[kk][ty*8+4];
      const float4 b0 = *(const float4*)&Bs[kk][tx*4];
      const float4 b1 = *(const float4*)&Bs[kk][64 + tx*4];
      const float a[8] = {a0.x,a0.y,a0.z,a0.w,a1.x,a1.y,a1.z,a1.w};
      const float b[8] = {b0.x,b0.y,b0.z,b0.w,b1.x,b1.y,b1.z,b1.w};
      #pragma unroll
      for (int i = 0; i < 8; i++)
        #pragma unroll
        for (int j = 0; j < 8; j++) c[i][j] += a[i]*b[j];
    }
    __syncthreads();
  }
  #pragma unroll
  for (int i = 0; i < 8; i++) {
    const int row = m0 + ty*8 + i;
    float4 o0 = make_float4(c[i][0],c[i][1],c[i][2],c[i][3]);
    float4 o1 = make_float4(c[i][4],c[i][5],c[i][6],c[i][7]);
    if (BIAS) {
      const float4 bb0 = *(const float4*)&bias[n0 + tx*4];
      const float4 bb1 = *(const float4*)&bias[n0 + 64 + tx*4];
      o0.x += bb0.x; o0.y += bb0.y; o0.z += bb0.z; o0.w += bb0.w;
      o1.x += bb1.x; o1.y += bb1.y; o1.z += bb1.z; o1.w += bb1.w;
    }
    if constexpr (sizeof(OutT) == 4) {
      *(float4*)&C[(size_t)row * N + n0 + tx*4] = o0;
      *(float4*)&C[(size_t)row * N + n0 + 64 + tx*4] = o1;
    } else {
      ushort4 u0, u1;
      u0.x = f2bf(o0.x); u0.y = f2bf(o0.y); u0.z = f2bf(o0.z); u0.w = f2bf(o0.w);
      u1.x = f2bf(o1.x); u1.y = f2bf(o1.y); u1.z = f2bf(o1.z); u1.w = f2bf(o1.w);
      *(ushort4*)&C[(size_t)row * N + n0 + tx*4] = u0;
      *(ushort4*)&C[(size_t)row * N + n0 + 64 + tx*4] = u1;
    }
  }
}

// ---------- k-feature + partial kv accumulation (fused, no k' materialization) ----------
// grid (NCHUNK, B*H), 256 threads. Thread owns feature column f = tid.
// partial[bh][chunk][f][0..63] = sum_t k'[t,f]*v[t,d]; [f][64] = sum_t k'[t,f]
__global__ __launch_bounds__(256, 1)
void kv_partial_kernel(const unsigned short* __restrict__ qkv, const float* __restrict__ proj,
                       float* __restrict__ partial) {
  const int c  = blockIdx.x;
  const int bh = blockIdx.y;
  const int b = bh >> 4, h = bh & 15;
  const int tid = threadIdx.x;
  __shared__ float ktT[64][36];    // [d][t] transposed k tile
  __shared__ float vt[32][68];     // [t][d] v tile
  __shared__ float stile[32][260]; // scores for row-max (rotated-scan stays conflict-light)
  __shared__ float pm[32][8];
  __shared__ float rmax[32];

  float pcol[64];
  #pragma unroll
  for (int d = 0; d < 64; d++) pcol[d] = proj[(size_t)(h*64 + d)*NF + tid];

  float acc[64];
  #pragma unroll
  for (int d = 0; d < 64; d++) acc[d] = 0.f;
  float accs = 0.f;

  const unsigned short* base = qkv + (size_t)(b*TSEQ + c*CH_T)*QKV_N + h*HD;
  for (int tt = 0; tt < CH_T/32; tt++) {
    const unsigned short* tb = base + (size_t)tt*32*QKV_N;
    #pragma unroll
    for (int i = 0; i < 2; i++) {
      const int job = tid + i*256;          // 512 jobs: (t, d4)
      const int t = job >> 4, d4 = (job & 15)*4;
      const ushort4 k4 = *(const ushort4*)&tb[(size_t)t*QKV_N + 1024 + d4];
      ktT[d4+0][t] = bf2f(k4.x); ktT[d4+1][t] = bf2f(k4.y);
      ktT[d4+2][t] = bf2f(k4.z); ktT[d4+3][t] = bf2f(k4.w);
      const ushort4 v4 = *(const ushort4*)&tb[(size_t)t*QKV_N + 2048 + d4];
      vt[t][d4+0] = bf2f(v4.x); vt[t][d4+1] = bf2f(v4.y);
      vt[t][d4+2] = bf2f(v4.z); vt[t][d4+3] = bf2f(v4.w);
    }
    __syncthreads();

    float sreg[32];
    #pragma unroll
    for (int t = 0; t < 32; t++) sreg[t] = 0.f;
    #pragma unroll
    for (int d = 0; d < 64; d++) {
      const float pv = pcol[d];
      #pragma unroll
      for (int t4 = 0; t4 < 32; t4 += 4) {
        const float4 k4 = *(const float4*)&ktT[d][t4];
        sreg[t4+0] += k4.x*pv;
        sreg[t4+1] += k4.y*pv;
        sreg[t4+2] += k4.z*pv;
        sreg[t4+3] += k4.w*pv;
      }
    }
    #pragma unroll
    for (int t = 0; t < 32; t++) stile[t][tid] = sreg[t];
    __syncthreads();
    {
      const int t = tid >> 3, seg = tid & 7;
      float m = -1e30f;
      #pragma unroll
      for (int i = 0; i < 32; i++)
        m = fmaxf(m, stile[t][seg*32 + ((i + seg) & 31)]);
      pm[t][seg] = m;
    }
    __syncthreads();
    if (tid < 32) {
      float m = pm[tid][0];
      #pragma unroll
      for (int s = 1; s < 8; s++) m = fmaxf(m, pm[tid][s]);
      rmax[tid] = m;
    }
    __syncthreads();
    #pragma unroll
    for (int t = 0; t < 32; t++) {
      const float kp = __expf(sreg[t] - rmax[t]);
      accs += kp;
      #pragma unroll
      for (int d4 = 0; d4 < 64; d4 += 4) {
        const float4 v4 = *(const float4*)&vt[t][d4];
        acc[d4+0] += kp*v4.x;
        acc[d4+1] += kp*v4.y;
        acc[d4+2] += kp*v4.z;
        acc[d4+3] += kp*v4.w;
      }
    }
    __syncthreads();
  }
  float* p = partial + ((size_t)(bh*NCHUNK + c)*NF + tid)*KVS;
  #pragma unroll
  for (int d4 = 0; d4 < 64; d4 += 4)
    *(float4*)&p[d4] = make_float4(acc[d4],acc[d4+1],acc[d4+2],acc[d4+3]);
  p[64] = accs;
}

// ---------------- reduce kv partials over 8 chunks ----------------
__global__ __launch_bounds__(256)
void kv_reduce_kernel(const float* __restrict__ partial, float* __restrict__ kv) {
  const size_t i = (size_t)blockIdx.x*256 + threadIdx.x;
  const size_t per_bh = (size_t)NF*KVS;
  const size_t bh = i / per_bh;
  const size_t j = i % per_bh;
  const float* p = partial + bh*NCHUNK*per_bh + j;
  float s = 0.f;
  #pragma unroll
  for (int c = 0; c < NCHUNK; c++) s += p[c*per_bh];
  kv[i] = s;
}

// ---------- q-feature + q'@kv + normalization (fused) ----------
// grid (TSEQ/32, B*H), 256 threads.
__global__ __launch_bounds__(256, 2)
void q_attn_kernel(const unsigned short* __restrict__ qkv, const float* __restrict__ proj,
                   const float* __restrict__ kv, float* __restrict__ attn) {
  const int tt = blockIdx.x;
  const int bh = blockIdx.y;
  const int b = bh >> 4, h = bh & 15;
  const int tid = threadIdx.x;
  __shared__ float qT[64][36];
  __shared__ float stile[32][260];  // scores -> q'
  __shared__ float pm[32][8];
  __shared__ float rmax[32];

  const int t0 = tt*32;
  const unsigned short* base = qkv + (size_t)(b*TSEQ + t0)*QKV_N + h*HD;
  float pcol[64];
  const float* ph = proj + (size_t)h*HD*NF + tid;
  #pragma unroll
  for (int d = 0; d < 64; d++) pcol[d] = ph[(size_t)d*NF];
  #pragma unroll
  for (int i = 0; i < 2; i++) {
    const int job = tid + i*256;
    const int t = job >> 4, d4 = (job & 15)*4;
    const ushort4 q4 = *(const ushort4*)&base[(size_t)t*QKV_N + d4];
    qT[d4+0][t] = bf2f(q4.x); qT[d4+1][t] = bf2f(q4.y);
    qT[d4+2][t] = bf2f(q4.z); qT[d4+3][t] = bf2f(q4.w);
  }
  __syncthreads();

  float sreg[32];
  #pragma unroll
  for (int t = 0; t < 32; t++) sreg[t] = 0.f;
  #pragma unroll
  for (int d = 0; d < 64; d++) {
    const float pv = pcol[d];
    #pragma unroll
    for (int t4 = 0; t4 < 32; t4 += 4) {
      const float4 q4 = *(const float4*)&qT[d][t4];
      sreg[t4+0] += q4.x*pv;
      sreg[t4+1] += q4.y*pv;
      sreg[t4+2] += q4.z*pv;
      sreg[t4+3] += q4.w*pv;
    }
  }
  #pragma unroll
  for (int t = 0; t < 32; t++) stile[t][tid] = sreg[t];
  __syncthreads();
  {
    const int t = tid >> 3, seg = tid & 7;
    float m = -1e30f;
    #pragma unroll
    for (int i = 0; i < 32; i++)
      m = fmaxf(m, stile[t][seg*32 + ((i + seg) & 31)]);
    pm[t][seg] = m;
  }
  __syncthreads();
  if (tid < 32) {
    float m = pm[tid][0];
    #pragma unroll
    for (int s = 1; s < 8; s++) m = fmaxf(m, pm[tid][s]);
    rmax[tid] = m;
  }
  __syncthreads();
  #pragma unroll
  for (int t = 0; t < 32; t++) stile[t][tid] = __expf(sreg[t] - rmax[t]);
  __syncthreads();

  // phase B: out[32][64] = q' @ kv ; denominator via kv column 64 (ksum)
  const float* kvh = kv + (size_t)bh*NF*KVS;
  const int rg = tid >> 4;          // rows rg*2, rg*2+1
  const int cg = tid & 15;          // cols cg*4..+3
  const int r0 = rg*2, r1 = r0 + 1;
  float o0x=0,o0y=0,o0z=0,o0w=0, o1x=0,o1y=0,o1z=0,o1w=0, den0=0, den1=0;
  for (int f4 = 0; f4 < NF; f4 += 4) {
    const float4 qa = *(const float4*)&stile[r0][f4];
    const float4 qb = *(const float4*)&stile[r1][f4];
    const float qa_[4] = {qa.x,qa.y,qa.z,qa.w};
    const float qb_[4] = {qb.x,qb.y,qb.z,qb.w};
    #pragma unroll
    for (int ff = 0; ff < 4; ff++) {
      const float* kvrow = kvh + (size_t)(f4+ff)*KVS;
      const float4 kvv = *(const float4*)&kvrow[cg*4];
      const float kd = kvrow[64];
      o0x += qa_[ff]*kvv.x; o0y += qa_[ff]*kvv.y; o0z += qa_[ff]*kvv.z; o0w += qa_[ff]*kvv.w;
      o1x += qb_[ff]*kvv.x; o1y += qb_[ff]*kvv.y; o1z += qb_[ff]*kvv.z; o1w += qb_[ff]*kvv.w;
      den0 += qa_[ff]*kd;
      den1 += qb_[ff]*kd;
    }
  }
  const float z0 = 1.f/(den0 + 1e-6f);
  const float z1 = 1.f/(den1 + 1e-6f);
  float* orow0 = attn + (size_t)(b*TSEQ + t0 + r0)*DIM_ + h*HD + cg*4;
  float* orow1 = attn + (size_t)(b*TSEQ + t0 + r1)*DIM_ + h*HD + cg*4;
  *(float4*)orow0 = make_float4(o0x*z0, o0y*z0, o0z*z0, o0w*z0);
  *(float4*)orow1 = make_float4(o1x*z1, o1y*z1, o1z*z1, o1w*z1);
}

extern "C" void kernel_launch(void* const* d_in, const int* in_sizes, int n_in,
                              void* d_out, int out_size, void* d_ws, size_t ws_size,
                              hipStream_t stream) {
  const float* x     = (const float*)d_in[0];
  const float* w_qkv = (const float*)d_in[1];
  const float* w_out = (const float*)d_in[2];
  const float* b_out = (const float*)d_in[3];
  const float* proj  = (const float*)d_in[4];
  float* out = (float*)d_out;

  // Workspace layout (bytes) — total 172,228,608 (~164 MiB):
  //   [0, 100663296)               qkv as bf16  (16384*3072*2)
  //   [100663296, 105119744)       kv fp32      (64*256*68*4)
  //   [105119744, 172228608)       attn fp32    (16384*1024*4)
  //     partial (64*8*256*68*4 = 35651584 B) ALIASES the attn region:
  //     partial lives during kernels 2-3, attn during kernels 4-5 (disjoint).
  char* ws = (char*)d_ws;
  unsigned short* qkv = (unsigned short*)ws;
  float* kvbuf   = (float*)(ws + 100663296);
  float* attn    = (float*)(ws + 105119744);
  float* partial = attn;   // alias, disjoint lifetime

  // 1) qkv = x @ w_qkv    [16384,1024]@[1024,3072] -> bf16
  sgemm128<false, unsigned short><<<dim3(QKV_N/128, TOK/128), 256, 0, stream>>>(
      x, w_qkv, nullptr, qkv, TOK, QKV_N, DIM_);
  // 2) fused k-feature map + partial kv/ksum per (chunk, head)
  kv_partial_kernel<<<dim3(NCHUNK, 64), 256, 0, stream>>>(qkv, proj, partial);
  // 3) reduce partials
  kv_reduce_kernel<<<dim3(64*NF*KVS/256), 256, 0, stream>>>(partial, kvbuf);
  // 4) fused q-feature map + q'@kv + 1/(q'.ksum) normalization
  q_attn_kernel<<<dim3(TSEQ/32, 64), 256, 0, stream>>>(qkv, proj, kvbuf, attn);
  // 5) out = attn @ w_out + b_out   (fp32 in/out)
  sgemm128<true, float><<<dim3(DIM_/128, TOK/128), 256, 0, stream>>>(
      attn, w_out, b_out, out, TOK, DIM_, DIM_);
}

// Round 3
// 1316.856 us; speedup vs baseline: 1.9481x; 1.9481x over previous
//
#include <hip/hip_runtime.h>

#define TOK   16384   // B*T
#define DIM_  1024
#define QKV_N 3072
#define NH    16
#define HD    64
#define NF    256
#define TSEQ  4096
#define NCHUNK 8
#define CH_T  512     // TSEQ/NCHUNK
#define KVS   68      // kv row stride (64 d + 1 ksum + pad)

typedef __attribute__((ext_vector_type(8))) short  bfrag8;   // 8 bf16 (4 VGPRs)
typedef __attribute__((ext_vector_type(4))) float  ffrag4;   // 4 fp32 acc
typedef __attribute__((ext_vector_type(8))) unsigned short u16x8;

// bf16 <-> f32 bit helpers (deterministic, RNE)
__device__ __forceinline__ float bf2f(unsigned short u) {
  union { unsigned int i; float f; } c; c.i = ((unsigned int)u) << 16; return c.f;
}
__device__ __forceinline__ unsigned short f2bf(float f) {
  union { float f; unsigned int i; } c; c.f = f;
  unsigned int r = c.i + 0x7FFFu + ((c.i >> 16) & 1u);
  return (unsigned short)(r >> 16);
}

__device__ __forceinline__ void gload16(const unsigned short* g, unsigned short* l) {
  __builtin_amdgcn_global_load_lds(
      (const __attribute__((address_space(1))) unsigned int*)g,
      (__attribute__((address_space(3))) unsigned int*)l, 16, 0, 0);
}

// ---------------- transpose + cast fp32 [R][C] -> bf16 [C][R] ----------------
__global__ __launch_bounds__(256)
void transpose_cast(const float* __restrict__ in, unsigned short* __restrict__ out,
                    int R, int C) {
  __shared__ float tile[32][33];
  const int bc = blockIdx.x * 32, br = blockIdx.y * 32;
  const int tx = threadIdx.x & 31, ty = threadIdx.x >> 5;   // 32x8
  #pragma unroll
  for (int i = 0; i < 32; i += 8)
    tile[ty + i][tx] = in[(size_t)(br + ty + i) * C + bc + tx];
  __syncthreads();
  #pragma unroll
  for (int i = 0; i < 32; i += 8)
    out[(size_t)(bc + ty + i) * R + br + tx] = f2bf(tile[tx][ty + i]);
}

// ---------------- bf16 MFMA GEMM: 128x128 tile, BK=32, 2x2 waves, 4x4 subtiles ----------------
// B is pre-transposed N-major bf16: BT[n][k]. SPLIT: A is fp32, split in-kernel
// into bf16 hi+lo (2 MFMA passes, ~fp32-accurate wrt A). !SPLIT: A is bf16,
// staged via global_load_lds.
template<bool SPLIT, bool BIAS, typename OutT>
__global__ __launch_bounds__(256, 2)
void gemm_mfma(const void* __restrict__ Avoid, const unsigned short* __restrict__ BT,
               const float* __restrict__ bias, OutT* __restrict__ C,
               int M, int N, int K) {
  __shared__ unsigned short ldsA [128 * 32];   // A hi tile, row-major [m][k]
  __shared__ unsigned short ldsAl[128 * 32];   // A lo tile (SPLIT only)
  __shared__ unsigned short ldsB [128 * 32];   // B^T tile, row-major [n][k]
  const int tid = threadIdx.x;
  const int m0 = blockIdx.y * 128, n0 = blockIdx.x * 128;
  const int w = tid >> 6, lane = tid & 63;
  const int wm = w >> 1, wn = w & 1;           // wave tile origin (rows wm*64, cols wn*64)
  const int lq = lane >> 4, lr = lane & 15;

  ffrag4 acc[4][4] = {};

  const int ch0 = tid, ch1 = tid + 256;        // 16B staging chunks (lane-ordered for global_load_lds)

  for (int k0 = 0; k0 < K; k0 += 32) {
    if constexpr (SPLIT) {
      const float* A = (const float*)Avoid;
      const int row = tid >> 1, half = tid & 1;
      const float* ap = A + (size_t)(m0 + row) * K + k0 + half * 16;
      float fe[16];
      #pragma unroll
      for (int v = 0; v < 4; v++) {
        const float4 f4v = ((const float4*)ap)[v];
        fe[v*4+0] = f4v.x; fe[v*4+1] = f4v.y; fe[v*4+2] = f4v.z; fe[v*4+3] = f4v.w;
      }
      u16x8 h0, h1, l0, l1;
      #pragma unroll
      for (int e = 0; e < 16; e++) {
        union { float f; unsigned u; } c; c.f = fe[e];
        const unsigned short h = (unsigned short)(c.u >> 16);   // truncation split (exact)
        union { unsigned u; float f; } hb; hb.u = ((unsigned)h) << 16;
        const unsigned short l = f2bf(fe[e] - hb.f);            // exact residual, RNE to bf16
        if (e < 8) { h0[e] = h; l0[e] = l; } else { h1[e-8] = h; l1[e-8] = l; }
      }
      unsigned short* dh = &ldsA [row * 32 + half * 16];
      unsigned short* dl = &ldsAl[row * 32 + half * 16];
      *(u16x8*)&dh[0] = h0; *(u16x8*)&dh[8] = h1;
      *(u16x8*)&dl[0] = l0; *(u16x8*)&dl[8] = l1;
    } else {
      const unsigned short* A = (const unsigned short*)Avoid;
      gload16(&A[(size_t)(m0 + (ch0 >> 2)) * K + k0 + (ch0 & 3) * 8], &ldsA[ch0 * 8]);
      gload16(&A[(size_t)(m0 + (ch1 >> 2)) * K + k0 + (ch1 & 3) * 8], &ldsA[ch1 * 8]);
    }
    gload16(&BT[(size_t)(n0 + (ch0 >> 2)) * K + k0 + (ch0 & 3) * 8], &ldsB[ch0 * 8]);
    gload16(&BT[(size_t)(n0 + (ch1 >> 2)) * K + k0 + (ch1 & 3) * 8], &ldsB[ch1 * 8]);
    __syncthreads();

    bfrag8 af[4], bf[4], alf[4];
    #pragma unroll
    for (int i = 0; i < 4; i++)
      af[i] = *(const bfrag8*)&ldsA[(wm * 64 + i * 16 + lr) * 32 + lq * 8];
    if constexpr (SPLIT) {
      #pragma unroll
      for (int i = 0; i < 4; i++)
        alf[i] = *(const bfrag8*)&ldsAl[(wm * 64 + i * 16 + lr) * 32 + lq * 8];
    }
    #pragma unroll
    for (int j = 0; j < 4; j++)
      bf[j] = *(const bfrag8*)&ldsB[(wn * 64 + j * 16 + lr) * 32 + lq * 8];

    #pragma unroll
    for (int i = 0; i < 4; i++)
      #pragma unroll
      for (int j = 0; j < 4; j++) {
        acc[i][j] = __builtin_amdgcn_mfma_f32_16x16x32_bf16(af[i], bf[j], acc[i][j], 0, 0, 0);
        if constexpr (SPLIT)
          acc[i][j] = __builtin_amdgcn_mfma_f32_16x16x32_bf16(alf[i], bf[j], acc[i][j], 0, 0, 0);
      }
    __syncthreads();
  }

  // epilogue: C/D layout col=lane&15, row=quad*4+reg
  #pragma unroll
  for (int i = 0; i < 4; i++) {
    #pragma unroll
    for (int j = 0; j < 4; j++) {
      const int row = m0 + wm * 64 + i * 16 + lq * 4;
      const int col = n0 + wn * 64 + j * 16 + lr;
      const float bb = BIAS ? bias[col] : 0.f;
      #pragma unroll
      for (int r = 0; r < 4; r++) {
        const float val = acc[i][j][r] + bb;
        if constexpr (sizeof(OutT) == 2) C[(size_t)(row + r) * N + col] = (OutT)f2bf(val);
        else                             C[(size_t)(row + r) * N + col] = (OutT)val;
      }
    }
  }
}

// ---------- k-feature + partial kv accumulation (fused, no k' materialization) ----------
__global__ __launch_bounds__(256, 1)
void kv_partial_kernel(const unsigned short* __restrict__ qkv, const float* __restrict__ proj,
                       float* __restrict__ partial) {
  const int c  = blockIdx.x;
  const int bh = blockIdx.y;
  const int b = bh >> 4, h = bh & 15;
  const int tid = threadIdx.x;
  __shared__ float ktT[64][36];
  __shared__ float vt[32][68];
  __shared__ float stile[32][260];
  __shared__ float pm[32][8];
  __shared__ float rmax[32];

  float pcol[64];
  #pragma unroll
  for (int d = 0; d < 64; d++) pcol[d] = proj[(size_t)(h*64 + d)*NF + tid];

  float acc[64];
  #pragma unroll
  for (int d = 0; d < 64; d++) acc[d] = 0.f;
  float accs = 0.f;

  const unsigned short* base = qkv + (size_t)(b*TSEQ + c*CH_T)*QKV_N + h*HD;
  for (int tt = 0; tt < CH_T/32; tt++) {
    const unsigned short* tb = base + (size_t)tt*32*QKV_N;
    #pragma unroll
    for (int i = 0; i < 2; i++) {
      const int job = tid + i*256;
      const int t = job >> 4, d4 = (job & 15)*4;
      const ushort4 k4 = *(const ushort4*)&tb[(size_t)t*QKV_N + 1024 + d4];
      ktT[d4+0][t] = bf2f(k4.x); ktT[d4+1][t] = bf2f(k4.y);
      ktT[d4+2][t] = bf2f(k4.z); ktT[d4+3][t] = bf2f(k4.w);
      const ushort4 v4 = *(const ushort4*)&tb[(size_t)t*QKV_N + 2048 + d4];
      vt[t][d4+0] = bf2f(v4.x); vt[t][d4+1] = bf2f(v4.y);
      vt[t][d4+2] = bf2f(v4.z); vt[t][d4+3] = bf2f(v4.w);
    }
    __syncthreads();

    float sreg[32];
    #pragma unroll
    for (int t = 0; t < 32; t++) sreg[t] = 0.f;
    #pragma unroll
    for (int d = 0; d < 64; d++) {
      const float pv = pcol[d];
      #pragma unroll
      for (int t4 = 0; t4 < 32; t4 += 4) {
        const float4 k4 = *(const float4*)&ktT[d][t4];
        sreg[t4+0] += k4.x*pv;
        sreg[t4+1] += k4.y*pv;
        sreg[t4+2] += k4.z*pv;
        sreg[t4+3] += k4.w*pv;
      }
    }
    #pragma unroll
    for (int t = 0; t < 32; t++) stile[t][tid] = sreg[t];
    __syncthreads();
    {
      const int t = tid >> 3, seg = tid & 7;
      float m = -1e30f;
      #pragma unroll
      for (int i = 0; i < 32; i++)
        m = fmaxf(m, stile[t][seg*32 + ((i + seg) & 31)]);
      pm[t][seg] = m;
    }
    __syncthreads();
    if (tid < 32) {
      float m = pm[tid][0];
      #pragma unroll
      for (int s = 1; s < 8; s++) m = fmaxf(m, pm[tid][s]);
      rmax[tid] = m;
    }
    __syncthreads();
    #pragma unroll
    for (int t = 0; t < 32; t++) {
      const float kp = __expf(sreg[t] - rmax[t]);
      accs += kp;
      #pragma unroll
      for (int d4 = 0; d4 < 64; d4 += 4) {
        const float4 v4 = *(const float4*)&vt[t][d4];
        acc[d4+0] += kp*v4.x;
        acc[d4+1] += kp*v4.y;
        acc[d4+2] += kp*v4.z;
        acc[d4+3] += kp*v4.w;
      }
    }
    __syncthreads();
  }
  float* p = partial + ((size_t)(bh*NCHUNK + c)*NF + tid)*KVS;
  #pragma unroll
  for (int d4 = 0; d4 < 64; d4 += 4)
    *(float4*)&p[d4] = make_float4(acc[d4],acc[d4+1],acc[d4+2],acc[d4+3]);
  p[64] = accs;
}

// ---------------- reduce kv partials over 8 chunks ----------------
__global__ __launch_bounds__(256)
void kv_reduce_kernel(const float* __restrict__ partial, float* __restrict__ kv) {
  const size_t i = (size_t)blockIdx.x*256 + threadIdx.x;
  const size_t per_bh = (size_t)NF*KVS;
  const size_t bh = i / per_bh;
  const size_t j = i % per_bh;
  const float* p = partial + bh*NCHUNK*per_bh + j;
  float s = 0.f;
  #pragma unroll
  for (int c = 0; c < NCHUNK; c++) s += p[c*per_bh];
  kv[i] = s;
}

// ---------- q-feature + q'@kv + normalization (fused); attn stored bf16 ----------
__global__ __launch_bounds__(256, 2)
void q_attn_kernel(const unsigned short* __restrict__ qkv, const float* __restrict__ proj,
                   const float* __restrict__ kv, unsigned short* __restrict__ attn) {
  const int tt = blockIdx.x;
  const int bh = blockIdx.y;
  const int b = bh >> 4, h = bh & 15;
  const int tid = threadIdx.x;
  __shared__ float qT[64][36];
  __shared__ float stile[32][260];
  __shared__ float pm[32][8];
  __shared__ float rmax[32];

  const int t0 = tt*32;
  const unsigned short* base = qkv + (size_t)(b*TSEQ + t0)*QKV_N + h*HD;
  float pcol[64];
  const float* ph = proj + (size_t)h*HD*NF + tid;
  #pragma unroll
  for (int d = 0; d < 64; d++) pcol[d] = ph[(size_t)d*NF];
  #pragma unroll
  for (int i = 0; i < 2; i++) {
    const int job = tid + i*256;
    const int t = job >> 4, d4 = (job & 15)*4;
    const ushort4 q4 = *(const ushort4*)&base[(size_t)t*QKV_N + d4];
    qT[d4+0][t] = bf2f(q4.x); qT[d4+1][t] = bf2f(q4.y);
    qT[d4+2][t] = bf2f(q4.z); qT[d4+3][t] = bf2f(q4.w);
  }
  __syncthreads();

  float sreg[32];
  #pragma unroll
  for (int t = 0; t < 32; t++) sreg[t] = 0.f;
  #pragma unroll
  for (int d = 0; d < 64; d++) {
    const float pv = pcol[d];
    #pragma unroll
    for (int t4 = 0; t4 < 32; t4 += 4) {
      const float4 q4 = *(const float4*)&qT[d][t4];
      sreg[t4+0] += q4.x*pv;
      sreg[t4+1] += q4.y*pv;
      sreg[t4+2] += q4.z*pv;
      sreg[t4+3] += q4.w*pv;
    }
  }
  #pragma unroll
  for (int t = 0; t < 32; t++) stile[t][tid] = sreg[t];
  __syncthreads();
  {
    const int t = tid >> 3, seg = tid & 7;
    float m = -1e30f;
    #pragma unroll
    for (int i = 0; i < 32; i++)
      m = fmaxf(m, stile[t][seg*32 + ((i + seg) & 31)]);
    pm[t][seg] = m;
  }
  __syncthreads();
  if (tid < 32) {
    float m = pm[tid][0];
    #pragma unroll
    for (int s = 1; s < 8; s++) m = fmaxf(m, pm[tid][s]);
    rmax[tid] = m;
  }
  __syncthreads();
  #pragma unroll
  for (int t = 0; t < 32; t++) stile[t][tid] = __expf(sreg[t] - rmax[t]);
  __syncthreads();

  const float* kvh = kv + (size_t)bh*NF*KVS;
  const int rg = tid >> 4;
  const int cg = tid & 15;
  const int r0 = rg*2, r1 = r0 + 1;
  float o0x=0,o0y=0,o0z=0,o0w=0, o1x=0,o1y=0,o1z=0,o1w=0, den0=0, den1=0;
  for (int f4 = 0; f4 < NF; f4 += 4) {
    const float4 qa = *(const float4*)&stile[r0][f4];
    const float4 qb = *(const float4*)&stile[r1][f4];
    const float qa_[4] = {qa.x,qa.y,qa.z,qa.w};
    const float qb_[4] = {qb.x,qb.y,qb.z,qb.w};
    #pragma unroll
    for (int ff = 0; ff < 4; ff++) {
      const float* kvrow = kvh + (size_t)(f4+ff)*KVS;
      const float4 kvv = *(const float4*)&kvrow[cg*4];
      const float kd = kvrow[64];
      o0x += qa_[ff]*kvv.x; o0y += qa_[ff]*kvv.y; o0z += qa_[ff]*kvv.z; o0w += qa_[ff]*kvv.w;
      o1x += qb_[ff]*kvv.x; o1y += qb_[ff]*kvv.y; o1z += qb_[ff]*kvv.z; o1w += qb_[ff]*kvv.w;
      den0 += qa_[ff]*kd;
      den1 += qb_[ff]*kd;
    }
  }
  const float z0 = 1.f/(den0 + 1e-6f);
  const float z1 = 1.f/(den1 + 1e-6f);
  unsigned short* orow0 = attn + (size_t)(b*TSEQ + t0 + r0)*DIM_ + h*HD + cg*4;
  unsigned short* orow1 = attn + (size_t)(b*TSEQ + t0 + r1)*DIM_ + h*HD + cg*4;
  ushort4 s0, s1;
  s0.x = f2bf(o0x*z0); s0.y = f2bf(o0y*z0); s0.z = f2bf(o0z*z0); s0.w = f2bf(o0w*z0);
  s1.x = f2bf(o1x*z1); s1.y = f2bf(o1y*z1); s1.z = f2bf(o1z*z1); s1.w = f2bf(o1w*z1);
  *(ushort4*)orow0 = s0;
  *(ushort4*)orow1 = s1;
}

extern "C" void kernel_launch(void* const* d_in, const int* in_sizes, int n_in,
                              void* d_out, int out_size, void* d_ws, size_t ws_size,
                              hipStream_t stream) {
  const float* x     = (const float*)d_in[0];
  const float* w_qkv = (const float*)d_in[1];
  const float* w_out = (const float*)d_in[2];
  const float* b_out = (const float*)d_in[3];
  const float* proj  = (const float*)d_in[4];
  float* out = (float*)d_out;

  // Workspace layout (bytes) — total 147,062,784 (~140 MiB), < 172 MB known-good:
  //   [0,          100663296)  qkv bf16 (16384*3072)
  //   [100663296,  105119744)  kv fp32 (64*256*68)
  //   [105119744,  140771328)  region R (35,651,584 B):
  //       phase 1 (kernels 3-4): partial fp32 (64*8*256*68)   = 35,651,584 B
  //       phase 2 (kernels 5-7): attn bf16 (33,554,432 B) + woutT bf16 (2,097,152 B)
  //   [140771328,  147062784)  wqkvT bf16 (3072*1024)
  char* ws = (char*)d_ws;
  unsigned short* qkv   = (unsigned short*)ws;
  float*          kvbuf = (float*)(ws + 100663296);
  float*          partial = (float*)(ws + 105119744);
  unsigned short* attn  = (unsigned short*)(ws + 105119744);
  unsigned short* woutT = (unsigned short*)(ws + 105119744 + 33554432);
  unsigned short* wqkvT = (unsigned short*)(ws + 140771328);

  // 1) wqkvT = transpose(w_qkv) as bf16 [3072][1024]
  transpose_cast<<<dim3(QKV_N/32, DIM_/32), 256, 0, stream>>>(w_qkv, wqkvT, DIM_, QKV_N);
  // 2) qkv = x @ w_qkv via bf16 MFMA, A split hi+lo (fp32-accurate wrt x) -> bf16
  gemm_mfma<true, false, unsigned short><<<dim3(QKV_N/128, TOK/128), 256, 0, stream>>>(
      (const void*)x, wqkvT, nullptr, qkv, TOK, QKV_N, DIM_);
  // 3) fused k-feature map + partial kv/ksum per (chunk, head)
  kv_partial_kernel<<<dim3(NCHUNK, 64), 256, 0, stream>>>(qkv, proj, partial);
  // 4) reduce partials
  kv_reduce_kernel<<<dim3(64*NF*KVS/256), 256, 0, stream>>>(partial, kvbuf);
  // 5) woutT = transpose(w_out) as bf16 [1024][1024] (into region R, after reduce)
  transpose_cast<<<dim3(DIM_/32, DIM_/32), 256, 0, stream>>>(w_out, woutT, DIM_, DIM_);
  // 6) fused q-feature map + q'@kv + normalization -> attn bf16
  q_attn_kernel<<<dim3(TSEQ/32, 64), 256, 0, stream>>>(qkv, proj, kvbuf, attn);
  // 7) out = attn @ w_out + b_out via bf16 MFMA, fp32 out
  gemm_mfma<false, true, float><<<dim3(DIM_/128, TOK/128), 256, 0, stream>>>(
      (const void*)attn, woutT, b_out, out, TOK, DIM_, DIM_);
}

// Round 4
// 605.326 us; speedup vs baseline: 4.2379x; 2.1754x over previous
//
#include <hip/hip_runtime.h>

#define TOK   16384   // B*T
#define DIM_  1024
#define QKV_N 3072
#define NH    16
#define HD    64
#define NF    256
#define TSEQ  4096
#define NCHUNK 8
#define CH_T  512     // TSEQ/NCHUNK
#define KVS   68      // kv row stride (64 d + 1 ksum + pad)

typedef __attribute__((ext_vector_type(8))) short  bfrag8;   // 8 bf16 (4 VGPRs)
typedef __attribute__((ext_vector_type(4))) float  ffrag4;   // 4 fp32 acc
typedef __attribute__((ext_vector_type(8))) unsigned short u16x8;
typedef __attribute__((ext_vector_type(4))) unsigned short u16x4;

__device__ __forceinline__ float bf2f(unsigned short u) {
  union { unsigned int i; float f; } c; c.i = ((unsigned int)u) << 16; return c.f;
}
__device__ __forceinline__ unsigned short f2bf(float f) {
  union { float f; unsigned int i; } c; c.f = f;
  unsigned int r = c.i + 0x7FFFu + ((c.i >> 16) & 1u);
  return (unsigned short)(r >> 16);
}

__device__ __forceinline__ void gload16(const unsigned short* g, unsigned short* l) {
  __builtin_amdgcn_global_load_lds(
      (const __attribute__((address_space(1))) unsigned int*)g,
      (__attribute__((address_space(3))) unsigned int*)l, 16, 0, 0);
}

// ---------------- batched transpose + cast fp32 [R][C] -> bf16 [C][R] ----------------
__global__ __launch_bounds__(256)
void transpose_cast(const float* __restrict__ in, unsigned short* __restrict__ out,
                    int R, int C) {
  __shared__ float tile[32][33];
  const size_t batch_off = (size_t)blockIdx.z * R * C;
  const float* bin = in + batch_off;
  unsigned short* bout = out + batch_off;
  const int bc = blockIdx.x * 32, br = blockIdx.y * 32;
  const int tx = threadIdx.x & 31, ty = threadIdx.x >> 5;   // 32x8
  #pragma unroll
  for (int i = 0; i < 32; i += 8)
    tile[ty + i][tx] = bin[(size_t)(br + ty + i) * C + bc + tx];
  __syncthreads();
  #pragma unroll
  for (int i = 0; i < 32; i += 8)
    bout[(size_t)(bc + ty + i) * R + br + tx] = f2bf(tile[tx][ty + i]);
}

// ---------------- bf16 MFMA GEMM: 128x128 tile, BK=32, 2x2 waves, 4x4 subtiles ----------------
template<bool SPLIT, bool BIAS, typename OutT>
__global__ __launch_bounds__(256, 2)
void gemm_mfma(const void* __restrict__ Avoid, const unsigned short* __restrict__ BT,
               const float* __restrict__ bias, OutT* __restrict__ C,
               int M, int N, int K) {
  __shared__ unsigned short ldsA [128 * 32];
  __shared__ unsigned short ldsAl[128 * 32];
  __shared__ unsigned short ldsB [128 * 32];
  const int tid = threadIdx.x;
  const int m0 = blockIdx.y * 128, n0 = blockIdx.x * 128;
  const int w = tid >> 6, lane = tid & 63;
  const int wm = w >> 1, wn = w & 1;
  const int lq = lane >> 4, lr = lane & 15;

  ffrag4 acc[4][4] = {};
  const int ch0 = tid, ch1 = tid + 256;

  for (int k0 = 0; k0 < K; k0 += 32) {
    if constexpr (SPLIT) {
      const float* A = (const float*)Avoid;
      const int row = tid >> 1, half = tid & 1;
      const float* ap = A + (size_t)(m0 + row) * K + k0 + half * 16;
      float fe[16];
      #pragma unroll
      for (int v = 0; v < 4; v++) {
        const float4 f4v = ((const float4*)ap)[v];
        fe[v*4+0] = f4v.x; fe[v*4+1] = f4v.y; fe[v*4+2] = f4v.z; fe[v*4+3] = f4v.w;
      }
      u16x8 h0, h1, l0, l1;
      #pragma unroll
      for (int e = 0; e < 16; e++) {
        union { float f; unsigned u; } c; c.f = fe[e];
        const unsigned short h = (unsigned short)(c.u >> 16);
        union { unsigned u; float f; } hb; hb.u = ((unsigned)h) << 16;
        const unsigned short l = f2bf(fe[e] - hb.f);
        if (e < 8) { h0[e] = h; l0[e] = l; } else { h1[e-8] = h; l1[e-8] = l; }
      }
      unsigned short* dh = &ldsA [row * 32 + half * 16];
      unsigned short* dl = &ldsAl[row * 32 + half * 16];
      *(u16x8*)&dh[0] = h0; *(u16x8*)&dh[8] = h1;
      *(u16x8*)&dl[0] = l0; *(u16x8*)&dl[8] = l1;
    } else {
      const unsigned short* A = (const unsigned short*)Avoid;
      gload16(&A[(size_t)(m0 + (ch0 >> 2)) * K + k0 + (ch0 & 3) * 8], &ldsA[ch0 * 8]);
      gload16(&A[(size_t)(m0 + (ch1 >> 2)) * K + k0 + (ch1 & 3) * 8], &ldsA[ch1 * 8]);
    }
    gload16(&BT[(size_t)(n0 + (ch0 >> 2)) * K + k0 + (ch0 & 3) * 8], &ldsB[ch0 * 8]);
    gload16(&BT[(size_t)(n0 + (ch1 >> 2)) * K + k0 + (ch1 & 3) * 8], &ldsB[ch1 * 8]);
    __syncthreads();

    bfrag8 af[4], bf[4], alf[4];
    #pragma unroll
    for (int i = 0; i < 4; i++)
      af[i] = *(const bfrag8*)&ldsA[(wm * 64 + i * 16 + lr) * 32 + lq * 8];
    if constexpr (SPLIT) {
      #pragma unroll
      for (int i = 0; i < 4; i++)
        alf[i] = *(const bfrag8*)&ldsAl[(wm * 64 + i * 16 + lr) * 32 + lq * 8];
    }
    #pragma unroll
    for (int j = 0; j < 4; j++)
      bf[j] = *(const bfrag8*)&ldsB[(wn * 64 + j * 16 + lr) * 32 + lq * 8];

    #pragma unroll
    for (int i = 0; i < 4; i++)
      #pragma unroll
      for (int j = 0; j < 4; j++) {
        acc[i][j] = __builtin_amdgcn_mfma_f32_16x16x32_bf16(af[i], bf[j], acc[i][j], 0, 0, 0);
        if constexpr (SPLIT)
          acc[i][j] = __builtin_amdgcn_mfma_f32_16x16x32_bf16(alf[i], bf[j], acc[i][j], 0, 0, 0);
      }
    __syncthreads();
  }

  #pragma unroll
  for (int i = 0; i < 4; i++) {
    #pragma unroll
    for (int j = 0; j < 4; j++) {
      const int row = m0 + wm * 64 + i * 16 + lq * 4;
      const int col = n0 + wn * 64 + j * 16 + lr;
      const float bb = BIAS ? bias[col] : 0.f;
      #pragma unroll
      for (int r = 0; r < 4; r++) {
        const float val = acc[i][j][r] + bb;
        if constexpr (sizeof(OutT) == 2) C[(size_t)(row + r) * N + col] = (OutT)f2bf(val);
        else                             C[(size_t)(row + r) * N + col] = (OutT)val;
      }
    }
  }
}

// ---------- Stage A: MFMA k-feature + partial kv/ksum ----------
// grid (NCHUNK, B*H), 256 threads (4 waves).
// Z = K_tile[64t x 64d] @ P[64d x 256f] (wave w owns f range w*64..w*64+63)
// k' = exp(Z - rowmax); KV[f][d] += k'^T @ [V | 1] (ksum as col 64, N=80)
__global__ __launch_bounds__(256, 1)
void kv_mfma_kernel(const unsigned short* __restrict__ qkv,
                    const unsigned short* __restrict__ projT,  // [H][256f][64d] bf16
                    float* __restrict__ partial) {
  const int c = blockIdx.x, bh = blockIdx.y;
  const int b = bh >> 4, h = bh & 15;
  const int tid = threadIdx.x;
  const int w = tid >> 6, lane = tid & 63;
  const int lq = lane >> 4, lr = lane & 15;
  __shared__ unsigned short pT[256 * 72];   // P^T [f][d], stride 72
  __shared__ unsigned short kp[256 * 72];   // k'  [f][t], stride 72
  __shared__ unsigned short vT[80 * 72];    // V^T [d][t] (+ones row 64), stride 72
  __shared__ float wmax[64][4];
  __shared__ float rmax_s[64];

  // stage P^T (per-head, once)
  #pragma unroll
  for (int e = 0; e < 8; e++) {
    const int job = e * 256 + tid;
    const int f = job >> 3, d0 = (job & 7) * 8;
    const u16x8 v = *(const u16x8*)&projT[(size_t)h * (NF * HD) + f * 64 + d0];
    *(u16x8*)&pT[f * 72 + d0] = v;
  }
  // init vT rows 64..79 (ones row for ksum, zeros elsewhere)
  for (int idx = tid; idx < 16 * 72; idx += 256) {
    const int r = idx / 72, cc = idx % 72;
    vT[(64 + r) * 72 + cc] = (r == 0 && cc < 64) ? (unsigned short)0x3F80 : (unsigned short)0;
  }
  __syncthreads();

  ffrag4 acc2[4][5];
  #pragma unroll
  for (int i = 0; i < 4; i++)
    #pragma unroll
    for (int j = 0; j < 5; j++) acc2[i][j] = (ffrag4){0.f, 0.f, 0.f, 0.f};

  const size_t rowbase = (size_t)b * TSEQ + (size_t)c * CH_T;

  for (int tt = 0; tt < CH_T / 64; tt++) {
    const int t0 = tt * 64;
    // stage V^T (transposed, padded)
    #pragma unroll
    for (int e = 0; e < 2; e++) {
      const int job = e * 256 + tid;
      const int t = job >> 3, d0 = (job & 7) * 8;
      const u16x8 v = *(const u16x8*)&qkv[(rowbase + t0 + t) * QKV_N + 2048 + h * 64 + d0];
      #pragma unroll
      for (int q = 0; q < 8; q++) vT[(d0 + q) * 72 + t] = v[q];
    }
    // Z = K @ P (A fragments direct from global)
    ffrag4 accZ[4][4];
    #pragma unroll
    for (int i = 0; i < 4; i++)
      #pragma unroll
      for (int j = 0; j < 4; j++) accZ[i][j] = (ffrag4){0.f, 0.f, 0.f, 0.f};
    #pragma unroll
    for (int kc = 0; kc < 2; kc++) {
      bfrag8 af[4], bfg[4];
      #pragma unroll
      for (int i = 0; i < 4; i++)
        af[i] = *(const bfrag8*)&qkv[(rowbase + t0 + i * 16 + lr) * QKV_N + 1024 + h * 64 + kc * 32 + lq * 8];
      #pragma unroll
      for (int j = 0; j < 4; j++)
        bfg[j] = *(const bfrag8*)&pT[(w * 64 + j * 16 + lr) * 72 + kc * 32 + lq * 8];
      #pragma unroll
      for (int i = 0; i < 4; i++)
        #pragma unroll
        for (int j = 0; j < 4; j++)
          accZ[i][j] = __builtin_amdgcn_mfma_f32_16x16x32_bf16(af[i], bfg[j], accZ[i][j], 0, 0, 0);
    }
    // rowmax over f: local max over j, shuffle over 16 lanes (cols), cross-wave via LDS
    float pmx[4][4];
    #pragma unroll
    for (int i = 0; i < 4; i++)
      #pragma unroll
      for (int r = 0; r < 4; r++) {
        float m = accZ[i][0][r];
        m = fmaxf(m, accZ[i][1][r]); m = fmaxf(m, accZ[i][2][r]); m = fmaxf(m, accZ[i][3][r]);
        pmx[i][r] = m;
      }
    #pragma unroll
    for (int off = 1; off < 16; off <<= 1)
      #pragma unroll
      for (int i = 0; i < 4; i++)
        #pragma unroll
        for (int r = 0; r < 4; r++)
          pmx[i][r] = fmaxf(pmx[i][r], __shfl_xor(pmx[i][r], off, 64));
    if (lr == 0)
      #pragma unroll
      for (int i = 0; i < 4; i++)
        #pragma unroll
        for (int r = 0; r < 4; r++) wmax[i * 16 + lq * 4 + r][w] = pmx[i][r];
    __syncthreads();
    if (tid < 64)
      rmax_s[tid] = fmaxf(fmaxf(wmax[tid][0], wmax[tid][1]), fmaxf(wmax[tid][2], wmax[tid][3]));
    __syncthreads();
    // exp + pack k' into kp[f][t] (b64 writes along reg dim: conflict-free)
    #pragma unroll
    for (int i = 0; i < 4; i++) {
      const float4 rmv = *(const float4*)&rmax_s[i * 16 + lq * 4];
      const float rmarr[4] = {rmv.x, rmv.y, rmv.z, rmv.w};
      #pragma unroll
      for (int j = 0; j < 4; j++) {
        u16x4 pk;
        #pragma unroll
        for (int r = 0; r < 4; r++) pk[r] = f2bf(__expf(accZ[i][j][r] - rmarr[r]));
        *(u16x4*)&kp[(w * 64 + j * 16 + lr) * 72 + i * 16 + lq * 4] = pk;
      }
    }
    __syncthreads();
    // KV += k'^T @ [V | 1]
    #pragma unroll
    for (int kc = 0; kc < 2; kc++) {
      bfrag8 af2[4], bf2[5];
      #pragma unroll
      for (int i = 0; i < 4; i++)
        af2[i] = *(const bfrag8*)&kp[(w * 64 + i * 16 + lr) * 72 + kc * 32 + lq * 8];
      #pragma unroll
      for (int j = 0; j < 5; j++)
        bf2[j] = *(const bfrag8*)&vT[(j * 16 + lr) * 72 + kc * 32 + lq * 8];
      #pragma unroll
      for (int i = 0; i < 4; i++)
        #pragma unroll
        for (int j = 0; j < 5; j++)
          acc2[i][j] = __builtin_amdgcn_mfma_f32_16x16x32_bf16(af2[i], bf2[j], acc2[i][j], 0, 0, 0);
    }
    __syncthreads();
  }
  // write partial [bh][c][f][0..64]
  float* pbase = partial + (size_t)(bh * NCHUNK + c) * NF * KVS;
  #pragma unroll
  for (int i = 0; i < 4; i++)
    #pragma unroll
    for (int j = 0; j < 5; j++) {
      if (j == 4 && lr != 0) continue;
      const int col = j * 16 + lr;   // j==4,lr==0 -> 64 (ksum)
      #pragma unroll
      for (int r = 0; r < 4; r++)
        pbase[(size_t)(w * 64 + i * 16 + lq * 4 + r) * KVS + col] = acc2[i][j][r];
    }
}

// ---------------- reduce kv partials over 8 chunks ----------------
__global__ __launch_bounds__(256)
void kv_reduce_kernel(const float* __restrict__ partial, float* __restrict__ kv) {
  const size_t i = (size_t)blockIdx.x * 256 + threadIdx.x;
  const size_t per_bh = (size_t)NF * KVS;
  const size_t bh = i / per_bh;
  const size_t j = i % per_bh;
  const float* p = partial + bh * NCHUNK * per_bh + j;
  float s = 0.f;
  #pragma unroll
  for (int c = 0; c < NCHUNK; c++) s += p[c * per_bh];
  kv[i] = s;
}

// ---------- Stage B: MFMA q-feature + O = q' @ [KV | ksum] + normalize ----------
// grid (TSEQ/64, B*H), 256 threads (4 waves).
__global__ __launch_bounds__(256, 1)
void q_attn_mfma_kernel(const unsigned short* __restrict__ qkv,
                        const unsigned short* __restrict__ projT,
                        const float* __restrict__ kv,
                        unsigned short* __restrict__ attn) {
  const int tb = blockIdx.x, bh = blockIdx.y;
  const int b = bh >> 4, h = bh & 15;
  const int tid = threadIdx.x;
  const int w = tid >> 6, lane = tid & 63;
  const int lq = lane >> 4, lr = lane & 15;
  __shared__ unsigned short pT[256 * 72];    // P^T [f][d]
  __shared__ unsigned short qp[64 * 264];    // q'  [t][f], stride 264
  __shared__ unsigned short kvT[80 * 264];   // KV^T [d][f] (+ksum row 64)
  __shared__ float wmax[64][4];
  __shared__ float rmax_s[64];

  #pragma unroll
  for (int e = 0; e < 8; e++) {
    const int job = e * 256 + tid;
    const int f = job >> 3, d0 = (job & 7) * 8;
    const u16x8 v = *(const u16x8*)&projT[(size_t)h * (NF * HD) + f * 64 + d0];
    *(u16x8*)&pT[f * 72 + d0] = v;
  }
  // stage KV^T bf16 (thread f = tid owns one kv row)
  {
    const float* kvrow = kv + ((size_t)bh * NF + tid) * KVS;
    #pragma unroll
    for (int d0 = 0; d0 < 64; d0 += 4) {
      const float4 v = *(const float4*)&kvrow[d0];
      kvT[(d0 + 0) * 264 + tid] = f2bf(v.x);
      kvT[(d0 + 1) * 264 + tid] = f2bf(v.y);
      kvT[(d0 + 2) * 264 + tid] = f2bf(v.z);
      kvT[(d0 + 3) * 264 + tid] = f2bf(v.w);
    }
    kvT[64 * 264 + tid] = f2bf(kvrow[64]);
    // zero rows 65..79 (keep cols clean; results there are discarded anyway)
    for (int idx = tid; idx < 15 * 264; idx += 256)
      kvT[65 * 264 + idx] = 0;
  }
  __syncthreads();

  const size_t rowbase = (size_t)b * TSEQ + (size_t)tb * 64;
  // Z = Q @ P
  ffrag4 accZ[4][4];
  #pragma unroll
  for (int i = 0; i < 4; i++)
    #pragma unroll
    for (int j = 0; j < 4; j++) accZ[i][j] = (ffrag4){0.f, 0.f, 0.f, 0.f};
  #pragma unroll
  for (int kc = 0; kc < 2; kc++) {
    bfrag8 af[4], bfg[4];
    #pragma unroll
    for (int i = 0; i < 4; i++)
      af[i] = *(const bfrag8*)&qkv[(rowbase + i * 16 + lr) * QKV_N + 0 + h * 64 + kc * 32 + lq * 8];
    #pragma unroll
    for (int j = 0; j < 4; j++)
      bfg[j] = *(const bfrag8*)&pT[(w * 64 + j * 16 + lr) * 72 + kc * 32 + lq * 8];
    #pragma unroll
    for (int i = 0; i < 4; i++)
      #pragma unroll
      for (int j = 0; j < 4; j++)
        accZ[i][j] = __builtin_amdgcn_mfma_f32_16x16x32_bf16(af[i], bfg[j], accZ[i][j], 0, 0, 0);
  }
  // rowmax
  float pmx[4][4];
  #pragma unroll
  for (int i = 0; i < 4; i++)
    #pragma unroll
    for (int r = 0; r < 4; r++) {
      float m = accZ[i][0][r];
      m = fmaxf(m, accZ[i][1][r]); m = fmaxf(m, accZ[i][2][r]); m = fmaxf(m, accZ[i][3][r]);
      pmx[i][r] = m;
    }
  #pragma unroll
  for (int off = 1; off < 16; off <<= 1)
    #pragma unroll
    for (int i = 0; i < 4; i++)
      #pragma unroll
      for (int r = 0; r < 4; r++)
        pmx[i][r] = fmaxf(pmx[i][r], __shfl_xor(pmx[i][r], off, 64));
  if (lr == 0)
    #pragma unroll
    for (int i = 0; i < 4; i++)
      #pragma unroll
      for (int r = 0; r < 4; r++) wmax[i * 16 + lq * 4 + r][w] = pmx[i][r];
  __syncthreads();
  if (tid < 64)
    rmax_s[tid] = fmaxf(fmaxf(wmax[tid][0], wmax[tid][1]), fmaxf(wmax[tid][2], wmax[tid][3]));
  __syncthreads();
  // exp -> qp[t][f]
  #pragma unroll
  for (int i = 0; i < 4; i++) {
    const float4 rmv = *(const float4*)&rmax_s[i * 16 + lq * 4];
    const float rmarr[4] = {rmv.x, rmv.y, rmv.z, rmv.w};
    #pragma unroll
    for (int j = 0; j < 4; j++)
      #pragma unroll
      for (int r = 0; r < 4; r++)
        qp[(i * 16 + lq * 4 + r) * 264 + w * 64 + j * 16 + lr] = f2bf(__expf(accZ[i][j][r] - rmarr[r]));
  }
  __syncthreads();
  // O = q' @ [KV | ksum]; wave w owns m-tile w (16 t-rows)
  ffrag4 acc3[5];
  #pragma unroll
  for (int j = 0; j < 5; j++) acc3[j] = (ffrag4){0.f, 0.f, 0.f, 0.f};
  #pragma unroll
  for (int kc = 0; kc < 8; kc++) {
    const bfrag8 afq = *(const bfrag8*)&qp[(w * 16 + lr) * 264 + kc * 32 + lq * 8];
    #pragma unroll
    for (int j = 0; j < 5; j++) {
      const bfrag8 bf3 = *(const bfrag8*)&kvT[(j * 16 + lr) * 264 + kc * 32 + lq * 8];
      acc3[j] = __builtin_amdgcn_mfma_f32_16x16x32_bf16(afq, bf3, acc3[j], 0, 0, 0);
    }
  }
  // epilogue: den = col 64 (held by lr==0 of each quad), broadcast, normalize
  #pragma unroll
  for (int r = 0; r < 4; r++) {
    const float den = __shfl(acc3[4][r], lane & 48, 64);
    const float z = 1.f / (den + 1e-6f);
    const int t = tb * 64 + w * 16 + lq * 4 + r;
    unsigned short* orow = attn + ((size_t)b * TSEQ + t) * DIM_ + h * 64;
    #pragma unroll
    for (int j = 0; j < 4; j++)
      orow[j * 16 + lr] = f2bf(acc3[j][r] * z);
  }
}

extern "C" void kernel_launch(void* const* d_in, const int* in_sizes, int n_in,
                              void* d_out, int out_size, void* d_ws, size_t ws_size,
                              hipStream_t stream) {
  const float* x     = (const float*)d_in[0];
  const float* w_qkv = (const float*)d_in[1];
  const float* w_out = (const float*)d_in[2];
  const float* b_out = (const float*)d_in[3];
  const float* proj  = (const float*)d_in[4];
  float* out = (float*)d_out;

  // Workspace layout (bytes) — total 147,587,072 (~141 MiB):
  //   [0,          100663296)  qkv bf16 (16384*3072)
  //   [100663296,  105119744)  kv fp32 (64*256*68)
  //   [105119744,  140771328)  region R (35,651,584 B):
  //       phase 1 (kernels): partial fp32 (64*8*256*68)
  //       phase 2: attn bf16 (33,554,432) + woutT bf16 (2,097,152)
  //   [140771328,  147062784)  wqkvT bf16 (3072*1024)
  //   [147062784,  147587072)  projT bf16 (16*256*64)
  char* ws = (char*)d_ws;
  unsigned short* qkv   = (unsigned short*)ws;
  float*          kvbuf = (float*)(ws + 100663296);
  float*          partial = (float*)(ws + 105119744);
  unsigned short* attn  = (unsigned short*)(ws + 105119744);
  unsigned short* woutT = (unsigned short*)(ws + 105119744 + 33554432);
  unsigned short* wqkvT = (unsigned short*)(ws + 140771328);
  unsigned short* projT = (unsigned short*)(ws + 147062784);

  // transposes: w_qkv [1024,3072]->[3072,1024]; proj per-head [64,256]->[256,64]
  transpose_cast<<<dim3(QKV_N/32, DIM_/32, 1), 256, 0, stream>>>(w_qkv, wqkvT, DIM_, QKV_N);
  transpose_cast<<<dim3(NF/32, HD/32, NH), 256, 0, stream>>>(proj, projT, HD, NF);
  // 1) qkv = x @ w_qkv (split-A bf16 MFMA, fp32-accurate wrt x) -> bf16
  gemm_mfma<true, false, unsigned short><<<dim3(QKV_N/128, TOK/128), 256, 0, stream>>>(
      (const void*)x, wqkvT, nullptr, qkv, TOK, QKV_N, DIM_);
  // 2) MFMA k-feature + partial kv/ksum
  kv_mfma_kernel<<<dim3(NCHUNK, 64), 256, 0, stream>>>(qkv, projT, partial);
  // 3) reduce partials
  kv_reduce_kernel<<<dim3(64*NF*KVS/256), 256, 0, stream>>>(partial, kvbuf);
  // 4) woutT (into region R, after reduce freed partial)
  transpose_cast<<<dim3(DIM_/32, DIM_/32, 1), 256, 0, stream>>>(w_out, woutT, DIM_, DIM_);
  // 5) MFMA q-feature + q'@kv + normalize -> attn bf16
  q_attn_mfma_kernel<<<dim3(TSEQ/64, 64), 256, 0, stream>>>(qkv, projT, kvbuf, attn);
  // 6) out = attn @ w_out + b_out
  gemm_mfma<false, true, float><<<dim3(DIM_/128, TOK/128), 256, 0, stream>>>(
      (const void*)attn, woutT, b_out, out, TOK, DIM_, DIM_);
}